// Round 7
// baseline (95.147 us; speedup 1.0000x reference)
//
#include <hip/hip_runtime.h>
#include <stdint.h>

// Zhang-Suen skeletonization, fully fused single kernel. (32,512,512) fp32.
// 16 substeps (8 iters x 2), bit-packed in LDS, halo-redundant 64-row strips.
//
// R7 = R6 with the nontemporal store fixed to use a native clang vector type
// (HIP float4 is a class; __builtin_nontemporal_store requires scalar/vector).
//  - Trapezoid active range: substep k computes only rows [k, 96-k).
//  - Nontemporal loads (input, read-once) and stores (output, write-once).

constexpr int W = 512;
constexpr int H = 512;
constexpr int BATCH = 32;
constexpr int WPR = W / 64;            // 8 words per row
constexpr int RV = 64;                 // valid rows per block
constexpr int HALO = 16;               // halo rows each side (16 substeps)
constexpr int SR = RV + 2 * HALO;      // 96 strip rows
constexpr int STRIPS = H / RV;         // 8 strips per image
constexpr int NWORDS = SR * WPR;       // 768 interior words per strip
constexpr int THREADS = 1024;          // 16 waves
constexpr int NWAVES = THREADS / 64;

typedef float vf4 __attribute__((ext_vector_type(4)));

// LDS layout with guard border: rows -1..SR, cols -1..WPR (+1 pad word)
constexpr int LDW2 = WPR + 2 + 1;      // 11 u64 row stride (odd -> bank spread)
constexpr int SRB = SR + 2;            // 98 rows
constexpr int BUFN = SRB * LDW2;       // 1078 u64 per buffer

__device__ __forceinline__ int lidx(int r, int wc) {  // r in [-1,SR], wc in [-1,WPR]
    return (r + 1) * LDW2 + (wc + 1);
}

__device__ __forceinline__ void fadd(uint64_t a, uint64_t b, uint64_t c,
                                     uint64_t& s, uint64_t& cy) {
    uint64_t t = a ^ b;
    s = t ^ c;
    cy = (a & b) | (c & t);
}

// One bit-parallel substep for one interior word. C comes in by register;
// reads the other 8 neighbor words from LDS, writes newC to dst, returns it.
template <bool FIRST>
__device__ __forceinline__ uint64_t substep(const uint64_t* __restrict__ src,
                                            uint64_t* __restrict__ dst,
                                            int off, uint64_t C) {
    const uint64_t* p = src + off;
    uint64_t UL = p[-LDW2 - 1], U = p[-LDW2], UR = p[-LDW2 + 1];
    uint64_t L  = p[-1],                      R  = p[1];
    uint64_t DL = p[ LDW2 - 1], D = p[ LDW2], DR = p[ LDW2 + 1];

    // Neighbor planes: P2=N P3=NE P4=E P5=SE P6=S P7=SW P8=W P9=NW
    uint64_t p2 = U;
    uint64_t p3 = (U >> 1) | (UR << 63);
    uint64_t p4 = (C >> 1) | (R  << 63);
    uint64_t p5 = (D >> 1) | (DR << 63);
    uint64_t p6 = D;
    uint64_t p7 = (D << 1) | (DL >> 63);
    uint64_t p8 = (C << 1) | (L  >> 63);
    uint64_t p9 = (U << 1) | (UL >> 63);

    // ---- bcnt in [2,6] via CSA tree ----
    uint64_t s1, ca, s2, cb, t0, t1, u, v;
    fadd(p2, p3, p4, s1, ca);
    fadd(p5, p6, p7, s2, cb);
    uint64_t s3 = p8 ^ p9, cc = p8 & p9;
    fadd(s1, s2, s3, t0, t1);          // ones
    fadd(ca, cb, cc, u, v);            // twos + fours
    uint64_t b1 = t1 ^ u, w2 = t1 & u; // twos bit, carry
    uint64_t b2 = v ^ w2, b3 = v & w2; // fours bit, eights bit
    uint64_t bok = (b1 | b2) & ~(b3 | (t0 & b1 & b2));   // 2 <= bcnt <= 6

    // ---- acnt == 1 via balanced seen/conflict tree ----
    uint64_t a1 = ~p2 & p3, a2 = ~p3 & p4, a3 = ~p4 & p5, a4 = ~p5 & p6;
    uint64_t a5 = ~p6 & p7, a6 = ~p7 & p8, a7 = ~p8 & p9, a8 = ~p9 & p2;
    uint64_t t12 = a1 | a2, d12 = a1 & a2;
    uint64_t t34 = a3 | a4, d34 = a3 & a4;
    uint64_t t56 = a5 | a6, d56 = a5 & a6;
    uint64_t t78 = a7 | a8, d78 = a7 & a8;
    uint64_t s14 = t12 | t34, u14 = t12 & t34;
    uint64_t s58 = t56 | t78, u58 = t56 & t78;
    uint64_t seen = s14 | s58;
    uint64_t conf = (d12 | d34) | (d56 | d78) | (u14 | u58) | (s14 & s58);
    uint64_t exactly1 = seen & ~conf;

    uint64_t cA, cB;
    if (FIRST) {
        cA = ~(p2 & p4 & p6);
        cB = ~(p4 & p6 & p8);
    } else {
        cA = ~(p2 & p4 & p8);
        cB = ~(p2 & p6 & p8);
    }

    uint64_t del = C & bok & exactly1 & cA & cB;
    uint64_t newC = C & ~del;
    dst[off] = newC;
    return newC;
}

__global__ __launch_bounds__(THREADS) void skel_fused(const float* __restrict__ in,
                                                      float* __restrict__ out) {
    __shared__ uint64_t buf0[BUFN];
    __shared__ uint64_t buf1[BUFN];

    const int blk  = blockIdx.x;
    const int img  = blk >> 3;          // image 0..31
    const int sidx = blk & 7;           // strip 0..7
    const float* ibase = in  + (size_t)img * H * W;
    float*       obase = out + (size_t)img * H * W;

    const int t    = threadIdx.x;
    const int lane = t & 63;
    const int wv   = t >> 6;            // wave 0..15
    const int y0   = sidx * RV - HALO;  // first strip row (global, may be <0)

    // ---- zero both buffers (borders stay 0; interiors overwritten) ----
    for (int i = t; i < BUFN; i += THREADS) {
        buf0[i] = 0ull;
        buf1[i] = 0ull;
    }
    __syncthreads();

    // ---- binarize strip into buf0: each wave packs 4 words/iter via ballot ----
    for (int g = wv; g < NWORDS / 4; g += NWAVES) {   // 192 groups
        int r   = g >> 1;               // strip row 0..95
        int wcg = (g & 1) * 4;          // word-col group 0 or 4
        int gy  = y0 + r;
        if ((unsigned)gy < (unsigned)H) {             // wave-uniform
            const float* rp = ibase + gy * W + wcg * 64 + lane;
            uint64_t m0 = __ballot(__builtin_nontemporal_load(rp)       >= 0.5f);
            uint64_t m1 = __ballot(__builtin_nontemporal_load(rp + 64)  >= 0.5f);
            uint64_t m2 = __ballot(__builtin_nontemporal_load(rp + 128) >= 0.5f);
            uint64_t m3 = __ballot(__builtin_nontemporal_load(rp + 192) >= 0.5f);
            if (lane == 0) {
                uint64_t* q = &buf0[lidx(r, wcg)];
                q[0] = m0; q[1] = m1; q[2] = m2; q[3] = m3;
            }
        }
    }
    __syncthreads();

    // ---- 16 substeps in LDS, trapezoid active range, early-out (exact) ----
    const bool worker = (t < NWORDS);   // first 12 waves hold strip words
    const int  r   = t >> 3;            // 0..95 (workers)
    const int  wc  = t & 7;             // 0..7
    const int  off = worker ? lidx(r, wc) : lidx(0, 0);

    uint64_t creg = worker ? buf0[off] : 0ull;

    for (int it = 0; it < 8; ++it) {
        const int kA = 2 * it + 1;      // substep index of the 'first' pass
        // active rows: A -> [kA, 96-kA), B -> [kA+1, 95-kA)
        const bool actA = worker && (r >= kA)     && (r < SR - kA);
        const bool actB = worker && (r >= kA + 1) && (r < SR - 1 - kA);

        uint64_t n1 = creg;
        if (actA) n1 = substep<true>(buf0, buf1, off, creg);
        __syncthreads();
        uint64_t n2 = n1;
        if (actB) n2 = substep<false>(buf1, buf0, off, n1);
        uint64_t chg = (n1 ^ creg) | (n2 ^ n1);
        creg = n2;
        int any = __syncthreads_or((int)(chg != 0ull));
        if (!any) break;                // whole padded strip is a fixed point
    }

    // ---- unpack valid 64 rows to fp32, nontemporal 16B stores ----
    for (int g = wv; g < RV * WPR / 4; g += NWAVES) { // 128 groups of 256 px
        int r2    = g >> 1;             // valid row 0..63
        int halfw = (g & 1) * 4;        // word-col group 0 or 4
        int wcl   = halfw + (lane >> 4);
        uint64_t word = buf0[lidx(r2 + HALO, wcl)];   // 16-lane broadcast read
        int sh = (lane & 15) * 4;
        vf4 v;
        v.x = (word >> (sh + 0)) & 1ull ? 1.0f : 0.0f;
        v.y = (word >> (sh + 1)) & 1ull ? 1.0f : 0.0f;
        v.z = (word >> (sh + 2)) & 1ull ? 1.0f : 0.0f;
        v.w = (word >> (sh + 3)) & 1ull ? 1.0f : 0.0f;
        int gy = sidx * RV + r2;
        vf4* dp = (vf4*)(obase + gy * W + halfw * 64 + 4 * lane);
        __builtin_nontemporal_store(v, dp);
    }
}

extern "C" void kernel_launch(void* const* d_in, const int* in_sizes, int n_in,
                              void* d_out, int out_size, void* d_ws, size_t ws_size,
                              hipStream_t stream) {
    const float* in0 = (const float*)d_in[0];
    float* out = (float*)d_out;

    const int grid = BATCH * STRIPS;   // 256 blocks, one per (image, strip)
    skel_fused<<<grid, THREADS, 0, stream>>>(in0, out);
}

// Round 8
// 91.994 us; speedup vs baseline: 1.0343x; 1.0343x over previous
//
#include <hip/hip_runtime.h>
#include <stdint.h>

// Zhang-Suen skeletonization, fully fused single kernel. (32,512,512) fp32.
// 16 substeps (8 iters x 2), bit-packed in LDS, halo-redundant strips.
//
// R8 changes vs R7: reverted trapezoid + nt loads (measured net-negative).
// Strips shrunk to 32 valid rows (+16+16 halo = 64 rows = 512 words), block =
// 512 threads (every thread a substep worker), grid = 512 -> 2 blocks/CU so
// one block's substep VALU overlaps the other block's binarize/unpack memory
// phases (waves co-schedule VALU and VMEM on a CU for free).

constexpr int W = 512;
constexpr int H = 512;
constexpr int BATCH = 32;
constexpr int WPR = W / 64;            // 8 words per row
constexpr int RV = 32;                 // valid rows per block
constexpr int HALO = 16;               // halo rows each side (16 substeps)
constexpr int SR = RV + 2 * HALO;      // 64 strip rows
constexpr int STRIPS = H / RV;         // 16 strips per image
constexpr int NWORDS = SR * WPR;       // 512 interior words per strip
constexpr int THREADS = 512;           // 8 waves, 1 word/thread in substeps
constexpr int NWAVES = THREADS / 64;

typedef float vf4 __attribute__((ext_vector_type(4)));

// LDS layout with guard border: rows -1..SR, cols -1..WPR (+1 pad word)
constexpr int LDW2 = WPR + 2 + 1;      // 11 u64 row stride (odd -> bank spread)
constexpr int SRB = SR + 2;            // 66 rows
constexpr int BUFN = SRB * LDW2;       // 726 u64 per buffer (~5.8 KB)

__device__ __forceinline__ int lidx(int r, int wc) {  // r in [-1,SR], wc in [-1,WPR]
    return (r + 1) * LDW2 + (wc + 1);
}

__device__ __forceinline__ void fadd(uint64_t a, uint64_t b, uint64_t c,
                                     uint64_t& s, uint64_t& cy) {
    uint64_t t = a ^ b;
    s = t ^ c;
    cy = (a & b) | (c & t);
}

// One bit-parallel substep for one interior word. C comes in by register;
// reads the other 8 neighbor words from LDS, writes newC to dst, returns it.
template <bool FIRST>
__device__ __forceinline__ uint64_t substep(const uint64_t* __restrict__ src,
                                            uint64_t* __restrict__ dst,
                                            int off, uint64_t C) {
    const uint64_t* p = src + off;
    uint64_t UL = p[-LDW2 - 1], U = p[-LDW2], UR = p[-LDW2 + 1];
    uint64_t L  = p[-1],                      R  = p[1];
    uint64_t DL = p[ LDW2 - 1], D = p[ LDW2], DR = p[ LDW2 + 1];

    // Neighbor planes: P2=N P3=NE P4=E P5=SE P6=S P7=SW P8=W P9=NW
    uint64_t p2 = U;
    uint64_t p3 = (U >> 1) | (UR << 63);
    uint64_t p4 = (C >> 1) | (R  << 63);
    uint64_t p5 = (D >> 1) | (DR << 63);
    uint64_t p6 = D;
    uint64_t p7 = (D << 1) | (DL >> 63);
    uint64_t p8 = (C << 1) | (L  >> 63);
    uint64_t p9 = (U << 1) | (UL >> 63);

    // ---- bcnt in [2,6] via CSA tree ----
    uint64_t s1, ca, s2, cb, t0, t1, u, v;
    fadd(p2, p3, p4, s1, ca);
    fadd(p5, p6, p7, s2, cb);
    uint64_t s3 = p8 ^ p9, cc = p8 & p9;
    fadd(s1, s2, s3, t0, t1);          // ones
    fadd(ca, cb, cc, u, v);            // twos + fours
    uint64_t b1 = t1 ^ u, w2 = t1 & u; // twos bit, carry
    uint64_t b2 = v ^ w2, b3 = v & w2; // fours bit, eights bit
    uint64_t bok = (b1 | b2) & ~(b3 | (t0 & b1 & b2));   // 2 <= bcnt <= 6

    // ---- acnt == 1 via balanced seen/conflict tree ----
    uint64_t a1 = ~p2 & p3, a2 = ~p3 & p4, a3 = ~p4 & p5, a4 = ~p5 & p6;
    uint64_t a5 = ~p6 & p7, a6 = ~p7 & p8, a7 = ~p8 & p9, a8 = ~p9 & p2;
    uint64_t t12 = a1 | a2, d12 = a1 & a2;
    uint64_t t34 = a3 | a4, d34 = a3 & a4;
    uint64_t t56 = a5 | a6, d56 = a5 & a6;
    uint64_t t78 = a7 | a8, d78 = a7 & a8;
    uint64_t s14 = t12 | t34, u14 = t12 & t34;
    uint64_t s58 = t56 | t78, u58 = t56 & t78;
    uint64_t seen = s14 | s58;
    uint64_t conf = (d12 | d34) | (d56 | d78) | (u14 | u58) | (s14 & s58);
    uint64_t exactly1 = seen & ~conf;

    uint64_t cA, cB;
    if (FIRST) {
        cA = ~(p2 & p4 & p6);
        cB = ~(p4 & p6 & p8);
    } else {
        cA = ~(p2 & p4 & p8);
        cB = ~(p2 & p6 & p8);
    }

    uint64_t del = C & bok & exactly1 & cA & cB;
    uint64_t newC = C & ~del;
    dst[off] = newC;
    return newC;
}

__global__ __launch_bounds__(THREADS) void skel_fused(const float* __restrict__ in,
                                                      float* __restrict__ out) {
    __shared__ uint64_t buf0[BUFN];
    __shared__ uint64_t buf1[BUFN];

    const int blk  = blockIdx.x;
    const int img  = blk >> 4;          // image 0..31
    const int sidx = blk & 15;          // strip 0..15
    const float* ibase = in  + (size_t)img * H * W;
    float*       obase = out + (size_t)img * H * W;

    const int t    = threadIdx.x;
    const int lane = t & 63;
    const int wv   = t >> 6;            // wave 0..7
    const int y0   = sidx * RV - HALO;  // first strip row (global, may be <0)

    // ---- zero both buffers (borders stay 0; interiors overwritten) ----
    for (int i = t; i < BUFN; i += THREADS) {
        buf0[i] = 0ull;
        buf1[i] = 0ull;
    }
    __syncthreads();

    // ---- binarize strip into buf0: each wave packs 4 words/iter via ballot ----
    for (int g = wv; g < NWORDS / 4; g += NWAVES) {   // 128 groups
        int r   = g >> 1;               // strip row 0..63
        int wcg = (g & 1) * 4;          // word-col group 0 or 4
        int gy  = y0 + r;
        if ((unsigned)gy < (unsigned)H) {             // wave-uniform
            const float* rp = ibase + gy * W + wcg * 64 + lane;
            uint64_t m0 = __ballot(rp[0]   >= 0.5f);
            uint64_t m1 = __ballot(rp[64]  >= 0.5f);
            uint64_t m2 = __ballot(rp[128] >= 0.5f);
            uint64_t m3 = __ballot(rp[192] >= 0.5f);
            if (lane == 0) {
                uint64_t* q = &buf0[lidx(r, wcg)];
                q[0] = m0; q[1] = m1; q[2] = m2; q[3] = m3;
            }
        }
    }
    __syncthreads();

    // ---- 16 substeps in LDS, early-out at fixed point (exact) ----
    const int r   = t >> 3;             // 0..63 — every thread is a worker
    const int wc  = t & 7;              // 0..7
    const int off = lidx(r, wc);

    uint64_t creg = buf0[off];

    for (int it = 0; it < 8; ++it) {
        uint64_t n1 = substep<true>(buf0, buf1, off, creg);
        __syncthreads();
        uint64_t n2 = substep<false>(buf1, buf0, off, n1);
        uint64_t chg = (n1 ^ creg) | (n2 ^ n1);
        creg = n2;
        int any = __syncthreads_or((int)(chg != 0ull));
        if (!any) break;                // whole padded strip is a fixed point
    }

    // ---- unpack valid 32 rows to fp32, nontemporal 16B stores ----
    for (int g = wv; g < RV * WPR / 4; g += NWAVES) { // 64 groups of 256 px
        int r2    = g >> 1;             // valid row 0..31
        int halfw = (g & 1) * 4;        // word-col group 0 or 4
        int wcl   = halfw + (lane >> 4);
        uint64_t word = buf0[lidx(r2 + HALO, wcl)];   // 16-lane broadcast read
        int sh = (lane & 15) * 4;
        vf4 v;
        v.x = (word >> (sh + 0)) & 1ull ? 1.0f : 0.0f;
        v.y = (word >> (sh + 1)) & 1ull ? 1.0f : 0.0f;
        v.z = (word >> (sh + 2)) & 1ull ? 1.0f : 0.0f;
        v.w = (word >> (sh + 3)) & 1ull ? 1.0f : 0.0f;
        int gy = sidx * RV + r2;
        vf4* dp = (vf4*)(obase + gy * W + halfw * 64 + 4 * lane);
        __builtin_nontemporal_store(v, dp);
    }
}

extern "C" void kernel_launch(void* const* d_in, const int* in_sizes, int n_in,
                              void* d_out, int out_size, void* d_ws, size_t ws_size,
                              hipStream_t stream) {
    const float* in0 = (const float*)d_in[0];
    float* out = (float*)d_out;

    const int grid = BATCH * STRIPS;   // 512 blocks -> 2 per CU
    skel_fused<<<grid, THREADS, 0, stream>>>(in0, out);
}

// Round 9
// 90.737 us; speedup vs baseline: 1.0486x; 1.0139x over previous
//
#include <hip/hip_runtime.h>
#include <stdint.h>

// Zhang-Suen skeletonization, fully fused single kernel. (32,512,512) fp32.
// 16 substeps (8 iters x 2), bit-packed in LDS, halo-redundant 64-row strips.
//
// R9 = R5 structure (96-row strips, 1024 threads, 768 workers — best measured)
// + per-row last-changed timestamps enabling wave-uniform skip of locally
// converged regions. Skip word (r,*) at substep s iff rows r-1..r+1 unchanged
// during substeps s-1 AND s-2 (two-substep stability needed since rules
// alternate parity: state_s[w] = f_s(state_{s-3}[N]) = f_{s-2}(state_{s-3}[N])
// = state_{s-2}[w] = state_{s-1}[w]). Races on flags are conservative-only.

constexpr int W = 512;
constexpr int H = 512;
constexpr int BATCH = 32;
constexpr int WPR = W / 64;            // 8 words per row
constexpr int RV = 64;                 // valid rows per block
constexpr int HALO = 16;               // halo rows each side (16 substeps)
constexpr int SR = RV + 2 * HALO;      // 96 strip rows
constexpr int STRIPS = H / RV;         // 8 strips per image
constexpr int NWORDS = SR * WPR;       // 768 interior words per strip
constexpr int THREADS = 1024;          // 16 waves
constexpr int NWAVES = THREADS / 64;

// LDS layout with guard border: rows -1..SR, cols -1..WPR (+1 pad word)
constexpr int LDW2 = WPR + 2 + 1;      // 11 u64 row stride (odd -> bank spread)
constexpr int SRB = SR + 2;            // 98 rows (incl. guards)
constexpr int BUFN = SRB * LDW2;       // 1078 u64 per buffer

__device__ __forceinline__ int lidx(int r, int wc) {  // r in [-1,SR], wc in [-1,WPR]
    return (r + 1) * LDW2 + (wc + 1);
}

__device__ __forceinline__ void fadd(uint64_t a, uint64_t b, uint64_t c,
                                     uint64_t& s, uint64_t& cy) {
    uint64_t t = a ^ b;
    s = t ^ c;
    cy = (a & b) | (c & t);
}

// One bit-parallel substep for one interior word. C comes in by register;
// reads the other 8 neighbor words from LDS, writes newC to dst, returns it.
template <bool FIRST>
__device__ __forceinline__ uint64_t substep(const uint64_t* __restrict__ src,
                                            uint64_t* __restrict__ dst,
                                            int off, uint64_t C) {
    const uint64_t* p = src + off;
    uint64_t UL = p[-LDW2 - 1], U = p[-LDW2], UR = p[-LDW2 + 1];
    uint64_t L  = p[-1],                      R  = p[1];
    uint64_t DL = p[ LDW2 - 1], D = p[ LDW2], DR = p[ LDW2 + 1];

    // Neighbor planes: P2=N P3=NE P4=E P5=SE P6=S P7=SW P8=W P9=NW
    uint64_t p2 = U;
    uint64_t p3 = (U >> 1) | (UR << 63);
    uint64_t p4 = (C >> 1) | (R  << 63);
    uint64_t p5 = (D >> 1) | (DR << 63);
    uint64_t p6 = D;
    uint64_t p7 = (D << 1) | (DL >> 63);
    uint64_t p8 = (C << 1) | (L  >> 63);
    uint64_t p9 = (U << 1) | (UL >> 63);

    // ---- bcnt in [2,6] via CSA tree ----
    uint64_t s1, ca, s2, cb, t0, t1, u, v;
    fadd(p2, p3, p4, s1, ca);
    fadd(p5, p6, p7, s2, cb);
    uint64_t s3 = p8 ^ p9, cc = p8 & p9;
    fadd(s1, s2, s3, t0, t1);          // ones
    fadd(ca, cb, cc, u, v);            // twos + fours
    uint64_t b1 = t1 ^ u, w2 = t1 & u; // twos bit, carry
    uint64_t b2 = v ^ w2, b3 = v & w2; // fours bit, eights bit
    uint64_t bok = (b1 | b2) & ~(b3 | (t0 & b1 & b2));   // 2 <= bcnt <= 6

    // ---- acnt == 1 via balanced seen/conflict tree ----
    uint64_t a1 = ~p2 & p3, a2 = ~p3 & p4, a3 = ~p4 & p5, a4 = ~p5 & p6;
    uint64_t a5 = ~p6 & p7, a6 = ~p7 & p8, a7 = ~p8 & p9, a8 = ~p9 & p2;
    uint64_t t12 = a1 | a2, d12 = a1 & a2;
    uint64_t t34 = a3 | a4, d34 = a3 & a4;
    uint64_t t56 = a5 | a6, d56 = a5 & a6;
    uint64_t t78 = a7 | a8, d78 = a7 & a8;
    uint64_t s14 = t12 | t34, u14 = t12 & t34;
    uint64_t s58 = t56 | t78, u58 = t56 & t78;
    uint64_t seen = s14 | s58;
    uint64_t conf = (d12 | d34) | (d56 | d78) | (u14 | u58) | (s14 & s58);
    uint64_t exactly1 = seen & ~conf;

    uint64_t cA, cB;
    if (FIRST) {
        cA = ~(p2 & p4 & p6);
        cB = ~(p4 & p6 & p8);
    } else {
        cA = ~(p2 & p4 & p8);
        cB = ~(p2 & p6 & p8);
    }

    uint64_t del = C & bok & exactly1 & cA & cB;
    uint64_t newC = C & ~del;
    dst[off] = newC;
    return newC;
}

__global__ __launch_bounds__(THREADS) void skel_fused(const float* __restrict__ in,
                                                      float* __restrict__ out) {
    __shared__ uint64_t buf0[BUFN];
    __shared__ uint64_t buf1[BUFN];
    __shared__ int flags[SRB];          // last substep in which row changed; -1

    const int blk  = blockIdx.x;
    const int img  = blk >> 3;          // image 0..31
    const int sidx = blk & 7;           // strip 0..7
    const float* ibase = in  + (size_t)img * H * W;
    float*       obase = out + (size_t)img * H * W;

    const int t    = threadIdx.x;
    const int lane = t & 63;
    const int wv   = t >> 6;            // wave 0..15
    const int y0   = sidx * RV - HALO;  // first strip row (global, may be <0)

    // ---- zero buffers; init flags to -1 (guards stay -1 forever) ----
    for (int i = t; i < BUFN; i += THREADS) {
        buf0[i] = 0ull;
        buf1[i] = 0ull;
    }
    if (t < SRB) flags[t] = -1;
    __syncthreads();

    // ---- binarize strip into buf0: each wave packs 4 words/iter via ballot ----
    for (int g = wv; g < NWORDS / 4; g += NWAVES) {   // 192 groups
        int r   = g >> 1;               // strip row 0..95
        int wcg = (g & 1) * 4;          // word-col group 0 or 4
        int gy  = y0 + r;
        if ((unsigned)gy < (unsigned)H) {             // wave-uniform
            const float* rp = ibase + gy * W + wcg * 64 + lane;
            uint64_t m0 = __ballot(rp[0]   >= 0.5f);
            uint64_t m1 = __ballot(rp[64]  >= 0.5f);
            uint64_t m2 = __ballot(rp[128] >= 0.5f);
            uint64_t m3 = __ballot(rp[192] >= 0.5f);
            if (lane == 0) {
                uint64_t* q = &buf0[lidx(r, wcg)];
                q[0] = m0; q[1] = m1; q[2] = m2; q[3] = m3;
            }
        }
    }
    __syncthreads();

    // ---- 16 substeps in LDS, per-row stability skip + global early-out ----
    const bool worker = (t < NWORDS);   // first 12 waves hold strip words
    const int  r   = t >> 3;            // 0..95 (workers)
    const int  wc  = t & 7;             // 0..7
    const int  off = worker ? lidx(r, wc) : lidx(0, 0);
    const int  fr  = worker ? r + 1 : 1; // flags index of own row

    uint64_t creg = worker ? buf0[off] : 0ull;

    for (int it = 0; it < 8; ++it) {
        const int sA = 2 * it, sB = 2 * it + 1;

        uint64_t n1 = creg;
        if (worker) {
            int fm = max(max(flags[fr - 1], flags[fr]), flags[fr + 1]);
            if (__any(fm >= sA - 2)) {              // wave-uniform
                n1 = substep<true>(buf0, buf1, off, creg);
                if (n1 != creg) atomicMax(&flags[fr], sA);
            } else {
                buf1[off] = creg;                   // value provably unchanged
            }
        }
        __syncthreads();

        uint64_t n2 = n1;
        if (worker) {
            int fm = max(max(flags[fr - 1], flags[fr]), flags[fr + 1]);
            if (__any(fm >= sB - 2)) {              // wave-uniform
                n2 = substep<false>(buf1, buf0, off, n1);
                if (n2 != n1) atomicMax(&flags[fr], sB);
            } else {
                buf0[off] = n1;                     // value provably unchanged
            }
        }
        uint64_t chg = (n1 ^ creg) | (n2 ^ n1);
        creg = n2;
        int any = __syncthreads_or((int)(chg != 0ull));
        if (!any) break;                // whole padded strip is a fixed point
    }

    // ---- unpack valid 64 rows to fp32, float4 stores ----
    for (int g = wv; g < RV * WPR / 4; g += NWAVES) { // 128 groups of 256 px
        int r2    = g >> 1;             // valid row 0..63
        int halfw = (g & 1) * 4;        // word-col group 0 or 4
        int wcl   = halfw + (lane >> 4);
        uint64_t word = buf0[lidx(r2 + HALO, wcl)];   // 16-lane broadcast read
        int sh = (lane & 15) * 4;
        float4 v;
        v.x = (word >> (sh + 0)) & 1ull ? 1.0f : 0.0f;
        v.y = (word >> (sh + 1)) & 1ull ? 1.0f : 0.0f;
        v.z = (word >> (sh + 2)) & 1ull ? 1.0f : 0.0f;
        v.w = (word >> (sh + 3)) & 1ull ? 1.0f : 0.0f;
        int gy = sidx * RV + r2;
        *(float4*)(obase + gy * W + halfw * 64 + 4 * lane) = v;
    }
}

extern "C" void kernel_launch(void* const* d_in, const int* in_sizes, int n_in,
                              void* d_out, int out_size, void* d_ws, size_t ws_size,
                              hipStream_t stream) {
    const float* in0 = (const float*)d_in[0];
    float* out = (float*)d_out;

    const int grid = BATCH * STRIPS;   // 256 blocks, one per (image, strip)
    skel_fused<<<grid, THREADS, 0, stream>>>(in0, out);
}